// Round 1
// baseline (105.747 us; speedup 1.0000x reference)
//
#include <hip/hip_runtime.h>

// EPN layer: B=8, N=256, DH=32, DX=3, DQ=1, DE=8, H1=H2=32, DIN=80.
// layer1 = relu(Pa[i] + Pb'[j] + e_ij@W1e), Pb' has b1 folded in.
// b3 cancels in 0.5*(elec_ij - elec_ji).
//
// R1: remat. R3: fission. R5: AGPR accs. R6: MFMA layer-2, LDS Z (107.2us).
// R7-9: barrier-free k-split regressed (latency-starved gathers). R10: LDS
//   swizzle + global A-frags regressed (bundled w/ swizzle, barrier present).
// R11: ez f32x4 = neutral -> pair is latency/occupancy-bound (3 blocks/CU),
//   not issue-bound.
// R12: one-orientation E[i][j] + gate G -> half MLP work, LDS 43.5->22.5KB;
//   kernel C antisymmetrizes via L3-resident transpose read (106.8us).
// R13: kill the block-wide barrier: MFMA tiles made wave-local
//   (jt = wave*64 + nt*32 covers exactly the wave's own Z rows), W2t LDS
//   staging replaced by direct global A-frags (L1-hot, once/block) -> zero
//   cross-wave deps -> __syncthreads deleted; launch_bounds(256,5) caps
//   arch VGPR at 102 (+16 acc = 118 -> 4 blocks/CU vs 3). Layer-3 b2/W3
//   as float4 (8 loads vs 64). Theory: de-convoy waves + more of them.

#define NATOM 256
#define TOT_ATOMS 2048
#define ZS 40   // ushort elems per Z row: 80 B = 16B-aligned, 20-bank stride

typedef __bf16 bf16x8 __attribute__((ext_vector_type(8)));
typedef float  f32x16 __attribute__((ext_vector_type(16)));
typedef float  f32x4  __attribute__((ext_vector_type(4)));

__device__ __forceinline__ unsigned int pk2(float a, float b) {
    unsigned short lo = __builtin_bit_cast(unsigned short, (__bf16)a);
    unsigned short hi = __builtin_bit_cast(unsigned short, (__bf16)b);
    return (unsigned int)lo | ((unsigned int)hi << 16);
}

// ---- Kernel A: per-atom projections, P[atom][64]: c<32 = Pa, c>=32 = Pb+b1.
__global__ __launch_bounds__(256) void atom_proj_kernel(
    const float* __restrict__ x, const float* __restrict__ h,
    const float* __restrict__ q, const float* __restrict__ W1,
    const float* __restrict__ b1, float* __restrict__ P)
{
    const int a  = threadIdx.x >> 5;   // 0..7
    const int u  = threadIdx.x & 31;   // 0..31
    const int n0 = blockIdx.x * 8;

    __shared__ float sd[8][37];        // x(3), h(32), q(1), pad
    for (int idx = threadIdx.x; idx < 8 * 36; idx += 256) {
        const int aa = idx / 36, r = idx - aa * 36;
        const int n = n0 + aa;
        float v;
        if (r < 3)       v = x[n * 3 + r];
        else if (r < 35) v = h[n * 32 + (r - 3)];
        else             v = q[n];
        sd[aa][r] = v;
    }
    __syncthreads();

    float pa = 0.f, pb = b1[u];
#pragma unroll
    for (int r = 0; r < 36; ++r) {
        const float d = sd[a][r];
        pa += d * W1[r * 32 + u];
        pb += d * W1[(36 + r) * 32 + u];
    }
    const int n = n0 + a;
    P[(size_t)n * 64 + u]      = pa;
    P[(size_t)n * 64 + 32 + u] = pb;
}

// ---- Kernel B: one block per (b,i) row; computes E[i][j] = elec_ij (one
//      orientation) and gate G[i][j]. VALU layer-1 -> bf16 Zij in LDS ->
//      wave-local MFMA layer-2 (no barrier) -> per-lane layer-3 -> E row.
__global__ __launch_bounds__(256, 5) void elec_kernel(
    const float* __restrict__ e, const float* __restrict__ mask,
    const float* __restrict__ P, const float* __restrict__ W1,
    const float* __restrict__ W2, const float* __restrict__ b2,
    const float* __restrict__ W3, float* __restrict__ E,
    float* __restrict__ G)
{
    const int row = blockIdx.x;          // b*256 + i == atom index of i
    const int b   = row >> 8;
    const int j   = threadIdx.x;
    const int col = (b << 8) + j;        // atom index of j

    __shared__ unsigned short Zij[256 * ZS];   // 20 KB, wave-disjoint rows

    const int wave = threadIdx.x >> 6;
    const int lane = threadIdx.x & 63;
    const int lo = lane & 31;     // = u for A, = j-col for B/C
    const int h  = lane >> 5;     // k-half selector / C row offset

    // ---- per-pair scalars; gate goes straight to global G
    const float* ep = e + (size_t)(row * NATOM + j) * 8;
    const float4 ev0 = ((const float4*)ep)[0];
    const float4 ev1 = ((const float4*)ep)[1];
    const float m = mask[row * NATOM + j];
    const float mx = fmaxf(fmaxf(fmaxf(ev0.x, ev0.y), fmaxf(ev0.z, ev0.w)),
                           fmaxf(fmaxf(ev1.x, ev1.y), fmaxf(ev1.z, ev1.w)));
    G[(size_t)row * NATOM + j] = (mx > 1e-5f) ? 0.5f * m : 0.f;

    // ---- layer 1 (ij orientation only): z = relu(Pa[i] + Pb[j] + e@W1e)
    const float* Pi = P + (size_t)row * 64;   // uniform -> s_load
    const float* Pj = P + (size_t)col * 64;   // per-thread vector loads
#pragma unroll
    for (int kq = 0; kq < 8; ++kq) {
        const float4 pbj4 = ((const float4*)Pj)[8 + kq];
        const int k0 = kq * 4;

        f32x4 ez = {0.f, 0.f, 0.f, 0.f};
        ez += (*(const f32x4*)(W1 + (72 + 0) * 32 + k0)) * ev0.x;
        ez += (*(const f32x4*)(W1 + (72 + 1) * 32 + k0)) * ev0.y;
        ez += (*(const f32x4*)(W1 + (72 + 2) * 32 + k0)) * ev0.z;
        ez += (*(const f32x4*)(W1 + (72 + 3) * 32 + k0)) * ev0.w;
        ez += (*(const f32x4*)(W1 + (72 + 4) * 32 + k0)) * ev1.x;
        ez += (*(const f32x4*)(W1 + (72 + 5) * 32 + k0)) * ev1.y;
        ez += (*(const f32x4*)(W1 + (72 + 6) * 32 + k0)) * ev1.z;
        ez += (*(const f32x4*)(W1 + (72 + 7) * 32 + k0)) * ev1.w;

        const float z0 = fmaxf(Pi[k0 + 0] + pbj4.x + ez[0], 0.f);
        const float z1 = fmaxf(Pi[k0 + 1] + pbj4.y + ez[1], 0.f);
        const float z2 = fmaxf(Pi[k0 + 2] + pbj4.z + ez[2], 0.f);
        const float z3 = fmaxf(Pi[k0 + 3] + pbj4.w + ez[3], 0.f);

        *(uint2*)&Zij[j * ZS + k0] = make_uint2(pk2(z0, z1), pk2(z2, z3));
    }

    // ---- A-frags direct from W2 (4 KB, L1-hot after first block on CU).
    //      a0[t] = W2[(h*8+t)][lo], a1[t] = W2[(16+h*8+t)][lo] -- identical
    //      values the old LDS W2t staging produced, without cross-wave deps.
    bf16x8 a0, a1;
#pragma unroll
    for (int t = 0; t < 8; ++t) {
        a0[t] = (__bf16)W2[(h * 8 + t) * 32 + lo];
        a1[t] = (__bf16)W2[(16 + h * 8 + t) * 32 + lo];
    }

    // ---- layer 2 via MFMA, wave-local tiles: wave w consumes exactly the
    //      Z rows [w*64, w*64+64) its own lanes wrote -> no __syncthreads.
    //      In-wave LDS RAW ordering is enforced by compiler lgkmcnt waits.
#pragma unroll
    for (int nt = 0; nt < 2; ++nt) {
        const int jt = wave * 64 + nt * 32;      // wave-local j-tile base
        const int zo = (jt + lo) * ZS + h * 8;
        f32x16 cij = {0.f};
        const bf16x8 bz0 = *(const bf16x8*)&Zij[zo];
        const bf16x8 bz1 = *(const bf16x8*)&Zij[zo + 16];
        cij = __builtin_amdgcn_mfma_f32_32x32x16_bf16(a0, bz0, cij, 0, 0, 0);
        cij = __builtin_amdgcn_mfma_f32_32x32x16_bf16(a1, bz1, cij, 0, 0, 0);

        // layer 3: d = sum_u relu(C[u][j'] + b2[u]) * W3[u]
        // C row u = (reg&3) + 8*(reg>>2) + 4*h -> reg quad rq covers
        // u = 8*rq + 4*h + t, t=0..3 -> float4 loads.
        float d = 0.f;
#pragma unroll
        for (int rq = 0; rq < 4; ++rq) {
            const int u0 = 8 * rq + 4 * h;
            const float4 b2v = *(const float4*)&b2[u0];
            const float4 w3v = *(const float4*)&W3[u0];
            d += fmaxf(cij[4 * rq + 0] + b2v.x, 0.f) * w3v.x;
            d += fmaxf(cij[4 * rq + 1] + b2v.y, 0.f) * w3v.y;
            d += fmaxf(cij[4 * rq + 2] + b2v.z, 0.f) * w3v.z;
            d += fmaxf(cij[4 * rq + 3] + b2v.w, 0.f) * w3v.w;
        }
        d += __shfl_xor(d, 32, 64);              // full 32-u sum in both halves
        if (h == 0)
            E[(size_t)row * NATOM + jt + lo] = d; // coalesced 128B per wave
    }
}

// ---- Kernel C: q_i += sum_j G[i][j] * (E[i][j] - E[j][i])
__global__ __launch_bounds__(256) void antisym_kernel(
    const float* __restrict__ q, const float* __restrict__ E,
    const float* __restrict__ G, float* __restrict__ out)
{
    const int row = blockIdx.x;        // b*256 + i
    const int b   = row >> 8;
    const int i   = row & 255;
    const int j   = threadIdx.x;

    const float eij = E[(size_t)row * NATOM + j];                  // coalesced
    const float eji = E[(size_t)((b << 8) + j) * NATOM + i];       // transpose, L3
    const float g   = G[(size_t)row * NATOM + j];                  // coalesced
    float v = g * (eij - eji);

#pragma unroll
    for (int off = 1; off < 64; off <<= 1)
        v += __shfl_xor(v, off, 64);
    __shared__ float red[4];
    if ((threadIdx.x & 63) == 0) red[threadIdx.x >> 6] = v;
    __syncthreads();
    if (threadIdx.x == 0)
        out[row] = q[row] + (red[0] + red[1] + red[2] + red[3]);
}

extern "C" void kernel_launch(void* const* d_in, const int* in_sizes, int n_in,
                              void* d_out, int out_size, void* d_ws, size_t ws_size,
                              hipStream_t stream)
{
    const float* h    = (const float*)d_in[0];
    const float* e    = (const float*)d_in[1];
    const float* x    = (const float*)d_in[2];
    const float* q    = (const float*)d_in[3];
    const float* mask = (const float*)d_in[4];
    const float* W1   = (const float*)d_in[5];
    const float* b1   = (const float*)d_in[6];
    const float* W2   = (const float*)d_in[7];
    const float* b2   = (const float*)d_in[8];
    const float* W3   = (const float*)d_in[9];
    // b3 cancels in the antisymmetric difference.

    float* P = (float*)d_ws;            // [2048][64]        = 512 KB
    float* E = P + 64 * TOT_ATOMS;      // [2048][256]       = 2 MB
    float* G = E + (size_t)TOT_ATOMS * NATOM;  // [2048][256] = 2 MB

    atom_proj_kernel<<<256, 256, 0, stream>>>(x, h, q, W1, b1, P);
    elec_kernel<<<TOT_ATOMS, 256, 0, stream>>>(e, mask, P, W1, W2, b2, W3, E, G);
    antisym_kernel<<<TOT_ATOMS, 256, 0, stream>>>(q, E, G, (float*)d_out);
}